// Round 9
// baseline (4839.761 us; speedup 1.0000x reference)
//
#include <hip/hip_runtime.h>
#include <hip/hip_bf16.h>
#include <math.h>

// ---------------- dims ----------------
#define B_     8
#define L_     1024
#define BL_    8192
#define C_IN_  12
#define DM_    128
#define DS_    16
#define DC_    4
#define DI_    256
#define DTR_   8
#define NH_    4
#define HD_    32
#define LH_    128
#define FCH_   128
#define NCLS_  5

// ---------------- workspace layout (floats) ----------------
#define OFF_U      0u
#define OFF_XC     1048576u     // ends 3145728
#define OFF_DBL    3145728u     // ends 3473408
#define OFF_WPK    3473408u     // ends 3579136
#define OFF_WQ     3579136u     // packed lstm w_hh, 65536 floats, ends 3644672 (< delta)
#define OFF_DELTA  3670016u     // ends 5767168
#define OFF_YG     5767168u     // ends 7864320
#define OFF_XZ     7864320u     // ends 12058624
#define OFF_XG     12058624u    // ends 16252928 (dead after scan_lstm)
#define OFF_HL     0u           // ends 1048576
#define OFF_PL     4194304u     // ends 7340032  (over dead delta/yg)
#define OFF_PM     7340032u     // ends 10485760 (over dead xz head)
#define OFF_AO0    10485760u    // ends 11534336
#define OFF_AO1    11534336u    // ends 12582912 == AO0 + BL_*128
#define OFF_HM     12582912u    // ends 13631488 (over dead xg)
#define OFF_T0     13631488u    // ends 14680064
#define OFF_T1     14680064u    // ends 15728640
#define OFF_HLU    1048576u     // phase4, over dead xc
#define OFF_HMU    2097152u
#define OFF_POOL   16384000u
// wpk sublayout: WL@0 WM@49152 bL@98304 bM@98688 WIH@99072 BIH@105216

typedef float v2f __attribute__((ext_vector_type(2)));

static __device__ __forceinline__ float fexpf_(float x){ return __builtin_amdgcn_exp2f(x*1.44269504089f); }
static __device__ __forceinline__ float fsig(float x){ return __builtin_amdgcn_rcpf(1.f + fexpf_(-x)); }
static __device__ __forceinline__ float ftanh(float x){ return 1.f - 2.f*__builtin_amdgcn_rcpf(1.f + fexpf_(2.f*x)); }
static __device__ __forceinline__ float siluf(float x){ return x*fsig(x); }
static __device__ __forceinline__ float softplusf(float x){
  return (x > 0.f) ? x + log1pf(expf(-x)) : log1pf(expf(x));
}
static __device__ __forceinline__ float qx1(float x){   // lane ^ 1
  return __int_as_float(__builtin_amdgcn_mov_dpp(__float_as_int(x), 0xB1, 0xF, 0xF, true));
}
static __device__ __forceinline__ float qx2(float x){   // lane ^ 2
  return __int_as_float(__builtin_amdgcn_mov_dpp(__float_as_int(x), 0x4E, 0xF, 0xF, true));
}
static __device__ __forceinline__ float ror8(float x){  // (lane+8)%16
  return __int_as_float(__builtin_amdgcn_mov_dpp(__float_as_int(x), 0x128, 0xF, 0xF, true));
}
static __device__ __forceinline__ float ror4(float x){  // (lane+4)%16
  return __int_as_float(__builtin_amdgcn_mov_dpp(__float_as_int(x), 0x124, 0xF, 0xF, true));
}
static __device__ __forceinline__ float rhm(float x){   // row_half_mirror: p -> 7-p within 8
  return __int_as_float(__builtin_amdgcn_mov_dpp(__float_as_int(x), 0x141, 0xF, 0xF, true));
}

// ---------------- generic tiled fp32 GEMM (small/odd shapes) ----------------
__global__ __launch_bounds__(256) void gemm_kernel(
    const float* __restrict__ A, int lda,
    const float* __restrict__ W,
    const float* __restrict__ bias,
    float* __restrict__ C,
    int M, int N, int K, int act)
{
  __shared__ float As[64][17];
  __shared__ float Ws[16][65];
  const int tid = threadIdx.x;
  const int tx = tid & 15, ty = tid >> 4;
  const int m0 = blockIdx.y * 64, n0 = blockIdx.x * 64;
  float acc[4][4];
  #pragma unroll
  for (int i=0;i<4;i++)
    #pragma unroll
    for (int j=0;j<4;j++) acc[i][j]=0.f;

  for (int k0=0;k0<K;k0+=16){
    const int ar = tid >> 2, ac4 = (tid & 3) * 4;
    #pragma unroll
    for (int j=0;j<4;j++){
      int kk = k0 + ac4 + j;
      As[ar][ac4+j] = (kk < K) ? A[(size_t)(m0+ar)*lda + kk] : 0.f;
    }
    const int wc = tid & 63, wr0 = (tid >> 6) * 4;
    #pragma unroll
    for (int j=0;j<4;j++){
      int kk = k0 + wr0 + j;
      Ws[wr0+j][wc] = (kk < K && (n0+wc) < N) ? W[(size_t)kk*N + n0 + wc] : 0.f;
    }
    __syncthreads();
    #pragma unroll
    for (int kk=0;kk<16;kk++){
      float a[4], w[4];
      #pragma unroll
      for (int i=0;i<4;i++) a[i] = As[ty*4+i][kk];
      #pragma unroll
      for (int j=0;j<4;j++) w[j] = Ws[kk][tx*4+j];
      #pragma unroll
      for (int i=0;i<4;i++)
        #pragma unroll
        for (int j=0;j<4;j++)
          acc[i][j] = fmaf(a[i], w[j], acc[i][j]);
    }
    __syncthreads();
  }
  #pragma unroll
  for (int i=0;i<4;i++){
    int m = m0 + ty*4 + i;
    #pragma unroll
    for (int j=0;j<4;j++){
      int n = n0 + tx*4 + j;
      if (n < N){
        float v = acc[i][j] + (bias ? bias[n] : 0.f);
        if (act == 1) v = softplusf(v);
        C[(size_t)m*N + n] = v;
      }
    }
  }
}

// ---------------- 128x128-tile fp32 GEMM, 8x8/thread ----------------
__global__ __launch_bounds__(256,2) void gemm128_kernel(
    const float* __restrict__ A, int lda,
    const float* __restrict__ W,
    const float* __restrict__ bias,
    float* __restrict__ C,
    int M, int N, int K, int act)
{
  __shared__ float As[8][132];
  __shared__ float Ws[8][132];
  const int tid = threadIdx.x;
  const int tx = tid & 15, ty = tid >> 4;
  const int m0 = blockIdx.y * 128, n0 = blockIdx.x * 128;
  const int ar = tid >> 1, akq = (tid & 1) * 4;
  const int wkr = tid >> 5, wnc = (tid & 31) * 4;
  float acc[8][8];
  #pragma unroll
  for (int i=0;i<8;i++)
    #pragma unroll
    for (int j=0;j<8;j++) acc[i][j]=0.f;

  for (int k0=0;k0<K;k0+=8){
    float4 av = *(const float4*)&A[(size_t)(m0+ar)*lda + k0 + akq];
    float4 wv = *(const float4*)&W[(size_t)(k0+wkr)*N + n0 + wnc];
    __syncthreads();
    As[akq+0][ar]=av.x; As[akq+1][ar]=av.y; As[akq+2][ar]=av.z; As[akq+3][ar]=av.w;
    *(float4*)&Ws[wkr][wnc] = wv;
    __syncthreads();
    #pragma unroll
    for (int kk=0;kk<8;kk++){
      float4 a0 = *(const float4*)&As[kk][ty*8];
      float4 a1 = *(const float4*)&As[kk][ty*8+4];
      float4 w0 = *(const float4*)&Ws[kk][tx*4];
      float4 w1 = *(const float4*)&Ws[kk][64 + tx*4];
      float a[8] = {a0.x,a0.y,a0.z,a0.w,a1.x,a1.y,a1.z,a1.w};
      float w[8] = {w0.x,w0.y,w0.z,w0.w,w1.x,w1.y,w1.z,w1.w};
      #pragma unroll
      for (int i=0;i<8;i++)
        #pragma unroll
        for (int j=0;j<8;j++)
          acc[i][j] = fmaf(a[i], w[j], acc[i][j]);
    }
  }
  #pragma unroll
  for (int i=0;i<8;i++){
    int m = m0 + ty*8 + i;
    #pragma unroll
    for (int j=0;j<8;j++){
      int n = n0 + ((j<4) ? (tx*4 + j) : (64 + tx*4 + j - 4));
      float v = acc[i][j] + (bias ? bias[n] : 0.f);
      if (act == 1) v = softplusf(v);
      C[(size_t)m*N + n] = v;
    }
  }
}

// ---------------- causal depthwise conv(4) + silu ----------------
__global__ __launch_bounds__(256) void conv_silu_kernel(
    const float* __restrict__ xz, const float* __restrict__ conv_w,
    const float* __restrict__ conv_b, float* __restrict__ xc)
{
  int idx = blockIdx.x * 256 + threadIdx.x;
  if (idx >= BL_*DI_) return;
  int d = idx & (DI_-1);
  int bl = idx >> 8;
  int l = bl & (L_-1), b = bl >> 10;
  float acc = conv_b[d];
  #pragma unroll
  for (int k=0;k<DC_;k++){
    int lk = l - (DC_-1) + k;
    if (lk >= 0)
      acc = fmaf(xz[((size_t)((b<<10)|lk))*512 + d], conv_w[d*DC_+k], acc);
  }
  xc[idx] = siluf(acc);
}

// ---------------- pack: attn QKV weights + LSTM weights ----------------
// idx<65536: packed w_hh -> wq[tid][64] (tid=(g<<3)|p,
// slot = gate_type*16 + kk, src = w_hh[(16p+kk)*512 + gate_type*128 + g])
__global__ __launch_bounds__(256) void pack_kernel(
    const float* __restrict__ ca_w, const float* __restrict__ ca_b,
    const float* __restrict__ lstm_w_ih, const float* __restrict__ lstm_b,
    const float* __restrict__ lstm_w_hh,
    float* __restrict__ wpk, float* __restrict__ wq)
{
  int idx = blockIdx.x * 256 + threadIdx.x;
  if (idx < 65536){
    int tw = idx >> 6, slot = idx & 63;
    int gt = slot >> 4, kk = slot & 15;
    int g = tw >> 3, p = tw & 7;
    wq[idx] = lstm_w_hh[(size_t)(16*p + kk)*512 + gt*128 + g];
  }
  if (idx < 49152){
    int in = idx / 384, c = idx % 384;
    int seg = c >> 7, o = c & 127;
    int dL = (seg==0)?0:1;
    int iL = (seg==0)?0:((seg==1)?1:2);
    int dM = (seg==2)?1:0;
    int iM = (seg==0)?1:((seg==1)?2:0);
    wpk[idx]         = ca_w[(((size_t)(dL*4+iL))*128 + in)*128 + o];
    wpk[49152 + idx] = ca_w[(((size_t)(dM*4+iM))*128 + in)*128 + o];
    if (in == 0){
      wpk[98304 + c] = ca_b[(dL*4+iL)*128 + o];
      wpk[98688 + c] = ca_b[(dM*4+iM)*128 + o];
    }
    // permuted lstm input proj: col' = g*4 + q  <-  col = q*128 + g
    if (idx < 6144){
      int inr = idx >> 9, cp = idx & 511;
      int g = cp >> 2, q = cp & 3;
      wpk[99072 + idx] = lstm_w_ih[inr*512 + q*128 + g];
    }
    if (idx < 512){
      int g = idx >> 2, q = idx & 3;
      wpk[105216 + idx] = lstm_b[q*128 + g];
    }
  }
}

// ---------------- fused selective-scan + LSTM (1024 threads) ----------------
// blocks 0..31: scan (b=blk>>2, d0=(blk&3)*64); blocks 32..39: lstm (b=blk-32)
// LSTM: weight stream split across BOTH data paths (they drain concurrently):
//   gates i,f (128KB fp32) staged ONCE into LDS (stride-33 -> conflict-free b128)
//   gates g,o (128KB fp32) streamed from L2 via per-thread contiguous wq
// Per step: ~128KB LDS (~1024cyc) || ~128KB VMEM (~910cyc), vs 256KB VMEM before.
#define FMAG(hv, w_i, w_f, w_g, w_o) \
  ai = fmaf(hv.x, w_i.x, ai); af = fmaf(hv.x, w_f.x, af); ag = fmaf(hv.x, w_g.x, ag); ao = fmaf(hv.x, w_o.x, ao); \
  ai = fmaf(hv.y, w_i.y, ai); af = fmaf(hv.y, w_f.y, af); ag = fmaf(hv.y, w_g.y, ag); ao = fmaf(hv.y, w_o.y, ao); \
  ai = fmaf(hv.z, w_i.z, ai); af = fmaf(hv.z, w_f.z, af); ag = fmaf(hv.z, w_g.z, ag); ao = fmaf(hv.z, w_o.z, ao); \
  ai = fmaf(hv.w, w_i.w, ai); af = fmaf(hv.w, w_f.w, af); ag = fmaf(hv.w, w_g.w, ag); ao = fmaf(hv.w, w_o.w, ao);

#define RED8(a) a += qx1(a); a += qx2(a); a += rhm(a);

__global__ __launch_bounds__(1024)
void scan_lstm_kernel(
    const float* __restrict__ delta, const float* __restrict__ dbl,
    const float* __restrict__ xc, const float* __restrict__ xz,
    const float* __restrict__ A_log, const float* __restrict__ Dp,
    float* __restrict__ yg,
    const float* __restrict__ xg, const float* __restrict__ wq,
    float* __restrict__ HL)
{
  // 132KB union: scan carves {sdx[32][64]v2f, sBC[32][16]v2f, sz[32][64]f}
  // (7168 floats) ; lstm uses all 33792 floats as stride-33 weight store.
  __shared__ __align__(16) float smem[33792];
  __shared__ __align__(16) float lh[2][160];
  const int tid = threadIdx.x;

  if (blockIdx.x < 32){
    // ---------- selective scan ----------
    v2f*  sdx = (v2f*)smem;                 // [32][64]
    v2f*  sBC = (v2f*)(smem + 8192);        // [32][16]
    float* sz = smem + 8192 + 1024;         // [32][64]
    const int b = blockIdx.x >> 2;
    const int d0 = (blockIdx.x & 3) * 64;
    const int dl = tid >> 4, s = tid & 15;
    const float A = -expf(A_log[(d0+dl)*DS_ + s]);
    const float Dv = Dp[d0+dl];
    float h = 0.f;
    const size_t base = (size_t)b * L_;
    for (int t0=0; t0<L_; t0+=32){
      __syncthreads();
      #pragma unroll
      for (int i0=0;i0<2;i0++){
        int i = tid + i0*1024;
        int tl = i >> 6, e = i & 63;
        size_t r = base + t0 + tl;
        v2f dx; dx.x = delta[r*256 + d0 + e]; dx.y = xc[r*256 + d0 + e];
        sdx[tl*64 + e] = dx;
        sz[tl*64 + e] = xz[r*512 + 256 + d0 + e];
      }
      if (tid < 512){
        int tl = tid >> 4, e = tid & 15;
        size_t r = base + t0 + tl;
        v2f bcv; bcv.x = dbl[r*40 + DTR_ + e]; bcv.y = dbl[r*40 + DTR_ + DS_ + e];
        sBC[tl*16 + e] = bcv;
      }
      __syncthreads();
      #pragma unroll 4
      for (int j=0;j<32;j++){
        v2f dx = sdx[j*64 + dl];
        v2f bc = sBC[j*16 + s];
        float dlt = dx.x, xcv = dx.y;
        h = fmaf(fexpf_(dlt*A), h, (dlt*bc.x)*xcv);
        float pr = h * bc.y;
        pr += qx1(pr); pr += qx2(pr); pr += ror8(pr); pr += ror4(pr);
        if (s == 0){
          float y = pr + Dv * xcv;
          yg[(base + t0 + j)*256 + d0 + dl] = y * siluf(sz[j*64 + dl]);
        }
      }
    }
  } else {
    // ---------- LSTM: thread = (g:0..127 col, p:0..7 k-slice of 16) ----------
    // p = lane bits 0..2 -> reduce = qx1, qx2, row_half_mirror (all DPP)
    const int b = blockIdx.x - 32;
    const int p = tid & 7, g = tid >> 3;
    // stage gates i,f (wq slots 0..31) into LDS, stride 33:
    // bank(lane) = (33*tid + 4j) % 32 = (tid + 4j) % 32 -> conflict-free b128
    float* wl = smem + (size_t)tid * 33;
    {
      const float4* src = (const float4*)(wq + (size_t)tid * 64);
      #pragma unroll
      for (int j=0;j<8;j++) *(float4*)(wl + 4*j) = src[j];
    }
    const float* wgo = wq + (size_t)tid * 64 + 32;   // gates g,o stream from L2
    if (tid < 160) lh[0][tid] = 0.f;
    float creg = 0.f;
    const float* xpb = xg + (size_t)b * L_ * 512;
    float* HLb = HL + (size_t)b * L_ * 128;
    float4 xv = *(const float4*)(xpb + 4*g);
    __syncthreads();
    int cur = 0;
    for (int t=0;t<L_;t++){
      const float* hbp = &lh[cur][0];
      // logical h[16p+4jj+i] lives at 20p+4jj+i -> float4 reads at 20p+{0,4,8,12}
      // (address depends only on p -> 8 distinct 16B slots, broadcast to 8 lanes)
      float4 hA = *(const float4*)(hbp + 20*p);
      float4 hB = *(const float4*)(hbp + 20*p + 4);
      float4 hC = *(const float4*)(hbp + 20*p + 8);
      float4 hD = *(const float4*)(hbp + 20*p + 12);
      // gates i,f from LDS
      float4 wi0 = *(const float4*)(wl);
      float4 wi1 = *(const float4*)(wl + 4);
      float4 wi2 = *(const float4*)(wl + 8);
      float4 wi3 = *(const float4*)(wl + 12);
      float4 wf0 = *(const float4*)(wl + 16);
      float4 wf1 = *(const float4*)(wl + 20);
      float4 wf2 = *(const float4*)(wl + 24);
      float4 wf3 = *(const float4*)(wl + 28);
      // gates g,o from global (L2-resident, per-thread contiguous)
      float4 wg0 = *(const float4*)(wgo);
      float4 wg1 = *(const float4*)(wgo + 4);
      float4 wg2 = *(const float4*)(wgo + 8);
      float4 wg3 = *(const float4*)(wgo + 12);
      float4 wo0 = *(const float4*)(wgo + 16);
      float4 wo1 = *(const float4*)(wgo + 20);
      float4 wo2 = *(const float4*)(wgo + 24);
      float4 wo3 = *(const float4*)(wgo + 28);
      float ai=0.f, af=0.f, ag=0.f, ao=0.f;
      FMAG(hA, wi0, wf0, wg0, wo0)
      FMAG(hB, wi1, wf1, wg1, wo1)
      FMAG(hC, wi2, wf2, wg2, wo2)
      FMAG(hD, wi3, wf3, wg3, wo3)
      float4 xn;
      if (t+1 < L_) xn = *(const float4*)(xpb + (size_t)(t+1)*512 + 4*g);
      else { xn.x=0.f; xn.y=0.f; xn.z=0.f; xn.w=0.f; }
      RED8(ai) RED8(af) RED8(ag) RED8(ao)
      float cc = fsig(af + xv.y)*creg + fsig(ai + xv.x)*ftanh(ag + xv.z);
      float hv_ = fsig(ao + xv.w)*ftanh(cc);
      creg = cc;
      if (p == 0){
        lh[cur^1][g + 4*(g>>4)] = hv_;
        HLb[(size_t)t*128 + g] = hv_;
      }
      __syncthreads();
      cur ^= 1;
      xv = xn;
    }
  }
}

// ---------------- flash attention: 16-way key-split, float4 VMEM ----------
// grid (32, 32, 2): qtile(32 rows), b*4+h, dir. block 512: sp=tid>>5, row=tid&31
#define DOT4(qv, kv) d0 = fmaf(qv.x, kv.x, d0); d1 = fmaf(qv.y, kv.y, d1); \
                     d2 = fmaf(qv.z, kv.z, d2); d3 = fmaf(qv.w, kv.w, d3);
#define PV4(ov, vv)  ov.x = fmaf(p_, vv.x, ov.x); ov.y = fmaf(p_, vv.y, ov.y); \
                     ov.z = fmaf(p_, vv.z, ov.z); ov.w = fmaf(p_, vv.w, ov.w);
#define SC4(ov)      ov.x *= corr; ov.y *= corr; ov.z *= corr; ov.w *= corr;
#define ST2(idx, a, b) { v2f t_; t_.x = a; t_.y = b; po2[sp][row][idx] = t_; }

__global__ __launch_bounds__(512) __attribute__((amdgpu_waves_per_eu(2,4)))
void attn_kernel(
    const float* __restrict__ PL, const float* __restrict__ PM,
    float* __restrict__ AO)
{
  __shared__ v2f  po2[16][32][17];
  __shared__ float sml[16][32][2];
  const int tid = threadIdx.x;
  const int sp = tid >> 5, row = tid & 31;
  const int dir = blockIdx.z;
  const int bh = blockIdx.y;
  const int b = bh >> 2, hh = bh & 3;
  const int qg = blockIdx.x * 32 + row;
  const float* Qb; const float* Kb; const float* Vb;
  if (dir == 0){ Qb = PL;       Kb = PM;       Vb = PM + 128; }
  else         { Qb = PM + 256; Kb = PL + 128; Vb = PL + 256; }
  const size_t rowb = (size_t)b * L_;
  const float4* qp = (const float4*)(Qb + (rowb + qg)*384 + hh*32);
  float4 q0=qp[0], q1=qp[1], q2=qp[2], q3=qp[3], q4=qp[4], q5=qp[5], q6=qp[6], q7=qp[7];
  float4 o0,o1,o2,o3,o4,o5,o6,o7;
  o0.x=0;o0.y=0;o0.z=0;o0.w=0; o1=o0; o2=o0; o3=o0; o4=o0; o5=o0; o6=o0; o7=o0;
  float m = -1e30f, l = 0.f;
  const float scale = 0.17677669529663687f;  // 1/sqrt(32)
  for (int kk=0;kk<64;kk++){
    const int k = sp*64 + kk;
    const float4* kr = (const float4*)(Kb + (rowb + k)*384 + hh*32);
    float4 kA=kr[0],kB=kr[1],kC=kr[2],kD=kr[3],kE=kr[4],kF=kr[5],kG=kr[6],kH=kr[7];
    float d0=0.f,d1=0.f,d2=0.f,d3=0.f;
    DOT4(q0,kA) DOT4(q1,kB) DOT4(q2,kC) DOT4(q3,kD)
    DOT4(q4,kE) DOT4(q5,kF) DOT4(q6,kG) DOT4(q7,kH)
    float s4 = ((d0+d1)+(d2+d3))*scale;
    if (s4 > m + 8.f){        // defer-max: rare rescale
      float corr = fexpf_(m - s4);
      l *= corr;
      SC4(o0) SC4(o1) SC4(o2) SC4(o3) SC4(o4) SC4(o5) SC4(o6) SC4(o7)
      m = s4;
    }
    float p_ = fexpf_(s4 - m);
    l += p_;
    const float4* vr = (const float4*)(Vb + (rowb + k)*384 + hh*32);
    float4 vA=vr[0],vB=vr[1],vC=vr[2],vD=vr[3],vE=vr[4],vF=vr[5],vG=vr[6],vH=vr[7];
    PV4(o0,vA) PV4(o1,vB) PV4(o2,vC) PV4(o3,vD)
    PV4(o4,vE) PV4(o5,vF) PV4(o6,vG) PV4(o7,vH)
  }
  ST2(0,o0.x,o0.y)  ST2(1,o0.z,o0.w)  ST2(2,o1.x,o1.y)  ST2(3,o1.z,o1.w)
  ST2(4,o2.x,o2.y)  ST2(5,o2.z,o2.w)  ST2(6,o3.x,o3.y)  ST2(7,o3.z,o3.w)
  ST2(8,o4.x,o4.y)  ST2(9,o4.z,o4.w)  ST2(10,o5.x,o5.y) ST2(11,o5.z,o5.w)
  ST2(12,o6.x,o6.y) ST2(13,o6.z,o6.w) ST2(14,o7.x,o7.y) ST2(15,o7.z,o7.w)
  sml[sp][row][0] = m; sml[sp][row][1] = l;
  __syncthreads();
  // merge: thread = (row mr, d-pair dp)
  const int mr = tid >> 4, dp = tid & 15;
  float M = -1e30f;
  #pragma unroll
  for (int s2=0;s2<16;s2++) M = fmaxf(M, sml[s2][mr][0]);
  float Lt = 0.f;
  v2f acc; acc.x=0.f; acc.y=0.f;
  #pragma unroll
  for (int s2=0;s2<16;s2++){
    float w = fexpf_(sml[s2][mr][0] - M);
    Lt = fmaf(sml[s2][mr][1], w, Lt);
    v2f t = po2[s2][mr][dp];
    acc.x = fmaf(t.x, w, acc.x);
    acc.y = fmaf(t.y, w, acc.y);
  }
  float inv = __builtin_amdgcn_rcpf(Lt);
  float* op = AO + (size_t)dir*BL_*128 + (rowb + blockIdx.x*32 + mr)*128 + hh*32;
  v2f outv; outv.x = acc.x*inv; outv.y = acc.y*inv;
  *(v2f*)(op + 2*dp) = outv;
}

// ---------------- residual + LayerNorm ----------------
__global__ __launch_bounds__(64) void ln_kernel(
    const float* __restrict__ HL, const float* __restrict__ T0,
    const float* __restrict__ HM, const float* __restrict__ T1,
    const float* __restrict__ ln_g, const float* __restrict__ ln_b,
    float* __restrict__ HLu, float* __restrict__ HMu)
{
  const int row = blockIdx.x;
  const int which = blockIdx.y;
  const float* X = which ? HM : HL;
  const float* T = which ? T1 : T0;
  const float* g = ln_g + which*128;
  const float* bb = ln_b + which*128;
  float* O = which ? HMu : HLu;
  const int lane = threadIdx.x;
  float v0 = X[(size_t)row*128 + lane]      + T[(size_t)row*128 + lane];
  float v1 = X[(size_t)row*128 + 64 + lane] + T[(size_t)row*128 + 64 + lane];
  float s = v0 + v1, s2 = v0*v0 + v1*v1;
  #pragma unroll
  for (int off=1; off<64; off<<=1){ s += __shfl_xor(s,off); s2 += __shfl_xor(s2,off); }
  float mean = s * (1.f/128.f);
  float var = s2 * (1.f/128.f) - mean*mean;
  float r = rsqrtf(var + 1e-5f);
  O[(size_t)row*128 + lane]      = (v0 - mean)*r*g[lane]      + bb[lane];
  O[(size_t)row*128 + 64 + lane] = (v1 - mean)*r*g[64+lane]   + bb[64+lane];
}

// ---------------- mean pool ----------------
__global__ __launch_bounds__(128) void pool_kernel(
    const float* __restrict__ HMu, const float* __restrict__ HLu,
    float* __restrict__ pooled)
{
  const int whichhalf = blockIdx.x;
  const int b = blockIdx.y;
  const int d = threadIdx.x;
  const float* S = whichhalf ? HLu : HMu;
  float s = 0.f;
  for (int t=0;t<L_;t++) s += S[((size_t)b*L_ + t)*128 + d];
  pooled[b*256 + whichhalf*128 + d] = s * (1.f/1024.f);
}

// ---------------- final MLP ----------------
__global__ __launch_bounds__(128) void fc_kernel(
    const float* __restrict__ pooled,
    const float* __restrict__ fc1_w, const float* __restrict__ fc1_b,
    const float* __restrict__ fc2_w, const float* __restrict__ fc2_b,
    float* __restrict__ out)
{
  const int b = blockIdx.x;
  const int j = threadIdx.x;
  __shared__ float hid[128];
  float acc = fc1_b[j];
  for (int k=0;k<256;k++) acc = fmaf(pooled[b*256 + k], fc1_w[k*128 + j], acc);
  hid[j] = fmaxf(acc, 0.f);
  __syncthreads();
  if (j < NCLS_){
    float a = fc2_b[j];
    for (int k=0;k<128;k++) a = fmaf(hid[k], fc2_w[k*NCLS_ + j], a);
    out[b*NCLS_ + j] = a;
  }
}

extern "C" void kernel_launch(void* const* d_in, const int* in_sizes, int n_in,
                              void* d_out, int out_size, void* d_ws, size_t ws_size,
                              hipStream_t stream)
{
  const float* x            = (const float*)d_in[0];
  const float* mamba_proj_w = (const float*)d_in[1];
  const float* mamba_proj_b = (const float*)d_in[2];
  const float* in_proj_w    = (const float*)d_in[3];
  const float* conv_w       = (const float*)d_in[4];
  const float* conv_b       = (const float*)d_in[5];
  const float* x_proj_w     = (const float*)d_in[6];
  const float* dt_proj_w    = (const float*)d_in[7];
  const float* dt_proj_b    = (const float*)d_in[8];
  const float* A_log        = (const float*)d_in[9];
  const float* Dp           = (const float*)d_in[10];
  const float* out_proj_w   = (const float*)d_in[11];
  const float* lstm_w_ih    = (const float*)d_in[12];
  const float* lstm_w_hh    = (const float*)d_in[13];
  const float* lstm_b       = (const float*)d_in[14];
  const float* ca_w         = (const float*)d_in[15];
  const float* ca_b         = (const float*)d_in[16];
  const float* ln_g         = (const float*)d_in[17];
  const float* ln_b         = (const float*)d_in[18];
  const float* fc1_w        = (const float*)d_in[19];
  const float* fc1_b        = (const float*)d_in[20];
  const float* fc2_w        = (const float*)d_in[21];
  const float* fc2_b        = (const float*)d_in[22];

  float* ws     = (float*)d_ws;
  float* u      = ws + OFF_U;
  float* xc     = ws + OFF_XC;
  float* dbl    = ws + OFF_DBL;
  float* delta  = ws + OFF_DELTA;
  float* yg     = ws + OFF_YG;
  float* xz     = ws + OFF_XZ;
  float* xg     = ws + OFF_XG;
  float* HM     = ws + OFF_HM;
  float* HL     = ws + OFF_HL;
  float* wpk    = ws + OFF_WPK;
  float* wq     = ws + OFF_WQ;
  float* PLb    = ws + OFF_PL;
  float* PMb    = ws + OFF_PM;
  float* AObase = ws + OFF_AO0;
  float* AO0    = ws + OFF_AO0;
  float* AO1    = ws + OFF_AO1;
  float* T0     = ws + OFF_T0;
  float* T1     = ws + OFF_T1;
  float* HLu    = ws + OFF_HLU;
  float* HMu    = ws + OFF_HMU;
  float* pooled = ws + OFF_POOL;

  // ---- phase 0: weight packing ----
  pack_kernel<<<dim3(256),256,0,stream>>>(ca_w, ca_b, lstm_w_ih, lstm_b, lstm_w_hh, wpk, wq);

  // ---- phase 1: projections for both branches ----
  gemm_kernel<<<dim3(2,128),256,0,stream>>>(x, 12, mamba_proj_w, mamba_proj_b, u, BL_, 128, 12, 0);
  gemm128_kernel<<<dim3(4,64),256,0,stream>>>(u, 128, in_proj_w, nullptr, xz, BL_, 512, 128, 0);
  conv_silu_kernel<<<dim3(BL_*DI_/256),256,0,stream>>>(xz, conv_w, conv_b, xc);
  gemm_kernel<<<dim3(1,128),256,0,stream>>>(xc, 256, x_proj_w, nullptr, dbl, BL_, 40, 256, 0);
  gemm128_kernel<<<dim3(2,64),256,0,stream>>>(dbl, 40, dt_proj_w, dt_proj_b, delta, BL_, 256, 8, 1);
  gemm_kernel<<<dim3(8,128),256,0,stream>>>(x, 12, wpk + 99072, wpk + 105216, xg, BL_, 512, 12, 0);

  // ---- phase 2: both recurrences in one launch ----
  scan_lstm_kernel<<<dim3(40),1024,0,stream>>>(delta, dbl, xc, xz, A_log, Dp, yg,
                                               xg, wq, HL);

  // ---- phase 3: cross attention ----
  gemm128_kernel<<<dim3(1,64),256,0,stream>>>(yg, 256, out_proj_w, nullptr, HM, BL_, 128, 256, 0);
  gemm128_kernel<<<dim3(3,64),256,0,stream>>>(HL, 128, wpk,         wpk + 98304, PLb, BL_, 384, 128, 0);
  gemm128_kernel<<<dim3(3,64),256,0,stream>>>(HM, 128, wpk + 49152, wpk + 98688, PMb, BL_, 384, 128, 0);
  attn_kernel<<<dim3(32,32,2),512,0,stream>>>(PLb, PMb, AObase);
  gemm128_kernel<<<dim3(1,64),256,0,stream>>>(AO0, 128, ca_w + 3*16384, ca_b + 384, T0, BL_, 128, 128, 0);
  gemm128_kernel<<<dim3(1,64),256,0,stream>>>(AO1, 128, ca_w + 7*16384, ca_b + 896, T1, BL_, 128, 128, 0);

  // ---- phase 4: LN, pool, MLP ----
  ln_kernel<<<dim3(8192,2),64,0,stream>>>(HL, T0, HM, T1, ln_g, ln_b, HLu, HMu);
  pool_kernel<<<dim3(2,8),128,0,stream>>>(HMu, HLu, pooled);
  fc_kernel<<<dim3(8),128,0,stream>>>(pooled, fc1_w, fc1_b, fc2_w, fc2_b, (float*)d_out);
}

// Round 10
// 1623.586 us; speedup vs baseline: 2.9809x; 2.9809x over previous
//
#include <hip/hip_runtime.h>
#include <hip/hip_bf16.h>
#include <math.h>

// ---------------- dims ----------------
#define B_     8
#define L_     1024
#define BL_    8192
#define C_IN_  12
#define DM_    128
#define DS_    16
#define DC_    4
#define DI_    256
#define DTR_   8
#define NH_    4
#define HD_    32
#define LH_    128
#define FCH_   128
#define NCLS_  5

// ---------------- workspace layout (floats) ----------------
#define OFF_U      0u
#define OFF_XC     1048576u
#define OFF_DBL    3145728u
#define OFF_WPK    3473408u
#define OFF_WQ     3579136u     // packed lstm w_hh, 65536 floats, ends 3644672
#define OFF_DELTA  3670016u
#define OFF_YG     5767168u
#define OFF_XZ     7864320u
#define OFF_XG     12058624u
#define OFF_HL     0u
#define OFF_PL     4194304u
#define OFF_PM     7340032u
#define OFF_AO0    10485760u
#define OFF_AO1    11534336u    // == AO0 + BL_*128 (attn writes AObase+dir*1048576)
#define OFF_HM     12582912u
#define OFF_T0     13631488u
#define OFF_T1     14680064u
#define OFF_HLU    1048576u
#define OFF_HMU    2097152u
#define OFF_POOL   16384000u
// wpk sublayout: WL@0 WM@49152 bL@98304 bM@98688 WIH@99072 BIH@105216

typedef float v2f __attribute__((ext_vector_type(2)));
typedef float v4f __attribute__((ext_vector_type(4)));

static __device__ __forceinline__ float fexpf_(float x){ return __builtin_amdgcn_exp2f(x*1.44269504089f); }
static __device__ __forceinline__ float fsig(float x){ return __builtin_amdgcn_rcpf(1.f + fexpf_(-x)); }
static __device__ __forceinline__ float ftanh(float x){ return 1.f - 2.f*__builtin_amdgcn_rcpf(1.f + fexpf_(2.f*x)); }
static __device__ __forceinline__ float siluf(float x){ return x*fsig(x); }
static __device__ __forceinline__ float softplusf(float x){
  return (x > 0.f) ? x + log1pf(expf(-x)) : log1pf(expf(x));
}
static __device__ __forceinline__ float qx1(float x){   // lane ^ 1
  return __int_as_float(__builtin_amdgcn_mov_dpp(__float_as_int(x), 0xB1, 0xF, 0xF, true));
}
static __device__ __forceinline__ float qx2(float x){   // lane ^ 2
  return __int_as_float(__builtin_amdgcn_mov_dpp(__float_as_int(x), 0x4E, 0xF, 0xF, true));
}
static __device__ __forceinline__ float ror8(float x){  // (lane+8)%16
  return __int_as_float(__builtin_amdgcn_mov_dpp(__float_as_int(x), 0x128, 0xF, 0xF, true));
}
static __device__ __forceinline__ float ror4(float x){  // (lane+4)%16
  return __int_as_float(__builtin_amdgcn_mov_dpp(__float_as_int(x), 0x124, 0xF, 0xF, true));
}
static __device__ __forceinline__ float rhm(float x){   // row_half_mirror: p -> 7-p within 8
  return __int_as_float(__builtin_amdgcn_mov_dpp(__float_as_int(x), 0x141, 0xF, 0xF, true));
}

// ---------------- generic tiled fp32 GEMM (small/odd shapes) ----------------
__global__ __launch_bounds__(256) void gemm_kernel(
    const float* __restrict__ A, int lda,
    const float* __restrict__ W,
    const float* __restrict__ bias,
    float* __restrict__ C,
    int M, int N, int K, int act)
{
  __shared__ float As[64][17];
  __shared__ float Ws[16][65];
  const int tid = threadIdx.x;
  const int tx = tid & 15, ty = tid >> 4;
  const int m0 = blockIdx.y * 64, n0 = blockIdx.x * 64;
  float acc[4][4];
  #pragma unroll
  for (int i=0;i<4;i++)
    #pragma unroll
    for (int j=0;j<4;j++) acc[i][j]=0.f;

  for (int k0=0;k0<K;k0+=16){
    const int ar = tid >> 2, ac4 = (tid & 3) * 4;
    #pragma unroll
    for (int j=0;j<4;j++){
      int kk = k0 + ac4 + j;
      As[ar][ac4+j] = (kk < K) ? A[(size_t)(m0+ar)*lda + kk] : 0.f;
    }
    const int wc = tid & 63, wr0 = (tid >> 6) * 4;
    #pragma unroll
    for (int j=0;j<4;j++){
      int kk = k0 + wr0 + j;
      Ws[wr0+j][wc] = (kk < K && (n0+wc) < N) ? W[(size_t)kk*N + n0 + wc] : 0.f;
    }
    __syncthreads();
    #pragma unroll
    for (int kk=0;kk<16;kk++){
      float a[4], w[4];
      #pragma unroll
      for (int i=0;i<4;i++) a[i] = As[ty*4+i][kk];
      #pragma unroll
      for (int j=0;j<4;j++) w[j] = Ws[kk][tx*4+j];
      #pragma unroll
      for (int i=0;i<4;i++)
        #pragma unroll
        for (int j=0;j<4;j++)
          acc[i][j] = fmaf(a[i], w[j], acc[i][j]);
    }
    __syncthreads();
  }
  #pragma unroll
  for (int i=0;i<4;i++){
    int m = m0 + ty*4 + i;
    #pragma unroll
    for (int j=0;j<4;j++){
      int n = n0 + tx*4 + j;
      if (n < N){
        float v = acc[i][j] + (bias ? bias[n] : 0.f);
        if (act == 1) v = softplusf(v);
        C[(size_t)m*N + n] = v;
      }
    }
  }
}

// ---------------- 128x128-tile fp32 GEMM, 8x8/thread ----------------
__global__ __launch_bounds__(256,2) void gemm128_kernel(
    const float* __restrict__ A, int lda,
    const float* __restrict__ W,
    const float* __restrict__ bias,
    float* __restrict__ C,
    int M, int N, int K, int act)
{
  __shared__ float As[8][132];
  __shared__ float Ws[8][132];
  const int tid = threadIdx.x;
  const int tx = tid & 15, ty = tid >> 4;
  const int m0 = blockIdx.y * 128, n0 = blockIdx.x * 128;
  const int ar = tid >> 1, akq = (tid & 1) * 4;
  const int wkr = tid >> 5, wnc = (tid & 31) * 4;
  float acc[8][8];
  #pragma unroll
  for (int i=0;i<8;i++)
    #pragma unroll
    for (int j=0;j<8;j++) acc[i][j]=0.f;

  for (int k0=0;k0<K;k0+=8){
    float4 av = *(const float4*)&A[(size_t)(m0+ar)*lda + k0 + akq];
    float4 wv = *(const float4*)&W[(size_t)(k0+wkr)*N + n0 + wnc];
    __syncthreads();
    As[akq+0][ar]=av.x; As[akq+1][ar]=av.y; As[akq+2][ar]=av.z; As[akq+3][ar]=av.w;
    *(float4*)&Ws[wkr][wnc] = wv;
    __syncthreads();
    #pragma unroll
    for (int kk=0;kk<8;kk++){
      float4 a0 = *(const float4*)&As[kk][ty*8];
      float4 a1 = *(const float4*)&As[kk][ty*8+4];
      float4 w0 = *(const float4*)&Ws[kk][tx*4];
      float4 w1 = *(const float4*)&Ws[kk][64 + tx*4];
      float a[8] = {a0.x,a0.y,a0.z,a0.w,a1.x,a1.y,a1.z,a1.w};
      float w[8] = {w0.x,w0.y,w0.z,w0.w,w1.x,w1.y,w1.z,w1.w};
      #pragma unroll
      for (int i=0;i<8;i++)
        #pragma unroll
        for (int j=0;j<8;j++)
          acc[i][j] = fmaf(a[i], w[j], acc[i][j]);
    }
  }
  #pragma unroll
  for (int i=0;i<8;i++){
    int m = m0 + ty*8 + i;
    #pragma unroll
    for (int j=0;j<8;j++){
      int n = n0 + ((j<4) ? (tx*4 + j) : (64 + tx*4 + j - 4));
      float v = acc[i][j] + (bias ? bias[n] : 0.f);
      if (act == 1) v = softplusf(v);
      C[(size_t)m*N + n] = v;
    }
  }
}

// ---------------- causal depthwise conv(4) + silu ----------------
__global__ __launch_bounds__(256) void conv_silu_kernel(
    const float* __restrict__ xz, const float* __restrict__ conv_w,
    const float* __restrict__ conv_b, float* __restrict__ xc)
{
  int idx = blockIdx.x * 256 + threadIdx.x;
  if (idx >= BL_*DI_) return;
  int d = idx & (DI_-1);
  int bl = idx >> 8;
  int l = bl & (L_-1), b = bl >> 10;
  float acc = conv_b[d];
  #pragma unroll
  for (int k=0;k<DC_;k++){
    int lk = l - (DC_-1) + k;
    if (lk >= 0)
      acc = fmaf(xz[((size_t)((b<<10)|lk))*512 + d], conv_w[d*DC_+k], acc);
  }
  xc[idx] = siluf(acc);
}

// ---------------- pack: attn QKV weights + LSTM weights ----------------
__global__ __launch_bounds__(256) void pack_kernel(
    const float* __restrict__ ca_w, const float* __restrict__ ca_b,
    const float* __restrict__ lstm_w_ih, const float* __restrict__ lstm_b,
    const float* __restrict__ lstm_w_hh,
    float* __restrict__ wpk, float* __restrict__ wq)
{
  int idx = blockIdx.x * 256 + threadIdx.x;
  if (idx < 65536){
    int tw = idx >> 6, slot = idx & 63;
    int gt = slot >> 4, kk = slot & 15;
    int g = tw >> 3, p = tw & 7;
    wq[idx] = lstm_w_hh[(size_t)(16*p + kk)*512 + gt*128 + g];
  }
  if (idx < 49152){
    int in = idx / 384, c = idx % 384;
    int seg = c >> 7, o = c & 127;
    int dL = (seg==0)?0:1;
    int iL = (seg==0)?0:((seg==1)?1:2);
    int dM = (seg==2)?1:0;
    int iM = (seg==0)?1:((seg==1)?2:0);
    wpk[idx]         = ca_w[(((size_t)(dL*4+iL))*128 + in)*128 + o];
    wpk[49152 + idx] = ca_w[(((size_t)(dM*4+iM))*128 + in)*128 + o];
    if (in == 0){
      wpk[98304 + c] = ca_b[(dL*4+iL)*128 + o];
      wpk[98688 + c] = ca_b[(dM*4+iM)*128 + o];
    }
    if (idx < 6144){
      int inr = idx >> 9, cp = idx & 511;
      int g = cp >> 2, q = cp & 3;
      wpk[99072 + idx] = lstm_w_ih[inr*512 + q*128 + g];
    }
    if (idx < 512){
      int g = idx >> 2, q = idx & 3;
      wpk[105216 + idx] = lstm_b[q*128 + g];
    }
  }
}

// ---------------- fused selective-scan + LSTM (1024 threads) ----------------
// blocks 0..31: scan; 32..39: lstm.
// LSTM sync uses RAW asm ds ops + s_barrier (mutually program-ordered):
// NO compiler-visible fence in the loop -> weight loads are loop-invariant
// -> LICM hoists them -> RA can keep 64 weight floats in VGPRs (budget 128
// at 1 block/CU forced by the LDS pad).
#define FMAG4(hv, w_i, w_f, w_g, w_o) \
  ai = fmaf(hv[0], w_i[0], ai); af = fmaf(hv[0], w_f[0], af); ag = fmaf(hv[0], w_g[0], ag); ao = fmaf(hv[0], w_o[0], ao); \
  ai = fmaf(hv[1], w_i[1], ai); af = fmaf(hv[1], w_f[1], af); ag = fmaf(hv[1], w_g[1], ag); ao = fmaf(hv[1], w_o[1], ao); \
  ai = fmaf(hv[2], w_i[2], ai); af = fmaf(hv[2], w_f[2], af); ag = fmaf(hv[2], w_g[2], ag); ao = fmaf(hv[2], w_o[2], ao); \
  ai = fmaf(hv[3], w_i[3], ai); af = fmaf(hv[3], w_f[3], af); ag = fmaf(hv[3], w_g[3], ag); ao = fmaf(hv[3], w_o[3], ao);

#define RED8(a) a += qx1(a); a += qx2(a); a += rhm(a);

#define LSTM_STEP(tt, RD, WR) { \
  v4f hA,hB,hC,hD; \
  asm volatile("ds_read_b128 %0, %4 offset:0\n\t" \
               "ds_read_b128 %1, %4 offset:16\n\t" \
               "ds_read_b128 %2, %4 offset:32\n\t" \
               "ds_read_b128 %3, %4 offset:48\n\t" \
               "s_waitcnt lgkmcnt(0)" \
               : "=&v"(hA),"=&v"(hB),"=&v"(hC),"=&v"(hD) : "v"(RD)); \
  float ai=0.f, af=0.f, ag=0.f, ao=0.f; \
  FMAG4(hA, wi0, wf0, wg0, wo0) \
  FMAG4(hB, wi1, wf1, wg1, wo1) \
  FMAG4(hC, wi2, wf2, wg2, wo2) \
  FMAG4(hD, wi3, wf3, wg3, wo3) \
  float4 xn; \
  if ((tt)+1 < L_) xn = *(const float4*)(xpb + (size_t)((tt)+1)*512 + 4*g); \
  else { xn.x=0.f; xn.y=0.f; xn.z=0.f; xn.w=0.f; } \
  RED8(ai) RED8(af) RED8(ag) RED8(ao) \
  float cc = fsig(af + xv.y)*creg + fsig(ai + xv.x)*ftanh(ag + xv.z); \
  float hv_ = fsig(ao + xv.w)*ftanh(cc); \
  creg = cc; \
  if (p == 0){ \
    asm volatile("ds_write_b32 %0, %1" :: "v"(WR), "v"(hv_)); \
    HLb[(size_t)(tt)*128 + g] = hv_; \
  } \
  asm volatile("s_waitcnt lgkmcnt(0)\n\ts_barrier"); \
  xv = xn; \
}

__global__ __launch_bounds__(1024)
void scan_lstm_kernel(
    const float* __restrict__ delta, const float* __restrict__ dbl,
    const float* __restrict__ xc, const float* __restrict__ xz,
    const float* __restrict__ A_log, const float* __restrict__ Dp,
    float* __restrict__ yg,
    const float* __restrict__ xg, const float* __restrict__ wq,
    float* __restrict__ HL)
{
  __shared__ v2f  sdx[32][64];   // {delta, xc}  16 KB
  __shared__ v2f  sBC[32][16];   // {B, C}        4 KB
  __shared__ float sz[32][64];   //               8 KB
  // lh: float g stored at g + 4*(g>>4); reads at 80*p bytes (16B-aligned)
  __shared__ __align__(16) float lh[2][160];
  // occupancy forcing pad: never executed -> 1 block/CU -> VGPR budget 128
  __shared__ float pad_force[16384];
  const int tid = threadIdx.x;
  if ((int)blockIdx.x < 0){             // never true at runtime
    pad_force[tid] = xg[tid];
    HL[tid] = pad_force[tid ^ 1];
  }

  if (blockIdx.x < 32){
    // ---------- selective scan (exact R8 code) ----------
    const int b = blockIdx.x >> 2;
    const int d0 = (blockIdx.x & 3) * 64;
    const int dl = tid >> 4, s = tid & 15;
    const float A = -expf(A_log[(d0+dl)*DS_ + s]);
    const float Dv = Dp[d0+dl];
    float h = 0.f;
    const size_t base = (size_t)b * L_;
    for (int t0=0; t0<L_; t0+=32){
      __syncthreads();
      #pragma unroll
      for (int i0=0;i0<2;i0++){
        int i = tid + i0*1024;
        int tl = i >> 6, e = i & 63;
        size_t r = base + t0 + tl;
        v2f dx; dx.x = delta[r*256 + d0 + e]; dx.y = xc[r*256 + d0 + e];
        sdx[tl][e] = dx;
        sz[tl][e] = xz[r*512 + 256 + d0 + e];
      }
      if (tid < 512){
        int tl = tid >> 4, e = tid & 15;
        size_t r = base + t0 + tl;
        v2f bcv; bcv.x = dbl[r*40 + DTR_ + e]; bcv.y = dbl[r*40 + DTR_ + DS_ + e];
        sBC[tl][e] = bcv;
      }
      __syncthreads();
      #pragma unroll 4
      for (int j=0;j<32;j++){
        v2f dx = sdx[j][dl];
        v2f bc = sBC[j][s];
        float dlt = dx.x, xcv = dx.y;
        h = fmaf(fexpf_(dlt*A), h, (dlt*bc.x)*xcv);
        float pr = h * bc.y;
        pr += qx1(pr); pr += qx2(pr); pr += ror8(pr); pr += ror4(pr);
        if (s == 0){
          float y = pr + Dv * xcv;
          yg[(base + t0 + j)*256 + d0 + dl] = y * siluf(sz[j][dl]);
        }
      }
    }
  } else {
    // ---------- LSTM: thread = (g:0..127 col, p:0..7 k-slice of 16) ----------
    const int b = blockIdx.x - 32;
    const int p = tid & 7, g = tid >> 3;
    const float* wt = wq + (size_t)tid * 64;
    // loop-invariant weight loads: NO fence below until the loop's asm
    // (which has no memory clobber) -> hoistable & register-resident
    v4f wi0 = *(const v4f*)(wt);      v4f wi1 = *(const v4f*)(wt + 4);
    v4f wi2 = *(const v4f*)(wt + 8);  v4f wi3 = *(const v4f*)(wt + 12);
    v4f wf0 = *(const v4f*)(wt + 16); v4f wf1 = *(const v4f*)(wt + 20);
    v4f wf2 = *(const v4f*)(wt + 24); v4f wf3 = *(const v4f*)(wt + 28);
    v4f wg0 = *(const v4f*)(wt + 32); v4f wg1 = *(const v4f*)(wt + 36);
    v4f wg2 = *(const v4f*)(wt + 40); v4f wg3 = *(const v4f*)(wt + 44);
    v4f wo0 = *(const v4f*)(wt + 48); v4f wo1 = *(const v4f*)(wt + 52);
    v4f wo2 = *(const v4f*)(wt + 56); v4f wo3 = *(const v4f*)(wt + 60);
    asm volatile("" : "+v"(wi0),"+v"(wi1),"+v"(wi2),"+v"(wi3),
                      "+v"(wf0),"+v"(wf1),"+v"(wf2),"+v"(wf3));
    asm volatile("" : "+v"(wg0),"+v"(wg1),"+v"(wg2),"+v"(wg3),
                      "+v"(wo0),"+v"(wo1),"+v"(wo2),"+v"(wo3));
    // LDS byte addresses (LDS aperture is 4GB-aligned -> low 32 bits = offset)
    const unsigned lbase = (unsigned)(size_t)&lh[0][0];
    const unsigned rd0 = lbase + 80u*(unsigned)p;
    const unsigned rd1 = rd0 + 640u;
    const unsigned wr0 = lbase + 4u*(unsigned)(g + 4*(g>>4));
    const unsigned wr1 = wr0 + 640u;
    // init h buffer 0 via asm ds_write (DSE-proof)
    if (tid < 160){
      asm volatile("ds_write_b32 %0, %1" :: "v"(lbase + 4u*tid), "v"(0.f));
    }
    asm volatile("s_waitcnt lgkmcnt(0)\n\ts_barrier");
    float creg = 0.f;
    const float* xpb = xg + (size_t)b * L_ * 512;
    float* HLb = HL + (size_t)b * L_ * 128;
    float4 xv = *(const float4*)(xpb + 4*g);
    for (int t=0;t<L_;t+=2){
      LSTM_STEP(t,   rd0, wr1)     // read buf0, write buf1
      LSTM_STEP(t+1, rd1, wr0)     // read buf1, write buf0
    }
  }
}

// ---------------- flash attention: 16-way key-split, float4 VMEM ----------
#define DOT4(qv, kv) d0 = fmaf(qv.x, kv.x, d0); d1 = fmaf(qv.y, kv.y, d1); \
                     d2 = fmaf(qv.z, kv.z, d2); d3 = fmaf(qv.w, kv.w, d3);
#define PV4(ov, vv)  ov.x = fmaf(p_, vv.x, ov.x); ov.y = fmaf(p_, vv.y, ov.y); \
                     ov.z = fmaf(p_, vv.z, ov.z); ov.w = fmaf(p_, vv.w, ov.w);
#define SC4(ov)      ov.x *= corr; ov.y *= corr; ov.z *= corr; ov.w *= corr;
#define ST2(idx, a, b) { v2f t_; t_.x = a; t_.y = b; po2[sp][row][idx] = t_; }

__global__ __launch_bounds__(512) __attribute__((amdgpu_waves_per_eu(2,4)))
void attn_kernel(
    const float* __restrict__ PL, const float* __restrict__ PM,
    float* __restrict__ AO)
{
  __shared__ v2f  po2[16][32][17];
  __shared__ float sml[16][32][2];
  const int tid = threadIdx.x;
  const int sp = tid >> 5, row = tid & 31;
  const int dir = blockIdx.z;
  const int bh = blockIdx.y;
  const int b = bh >> 2, hh = bh & 3;
  const int qg = blockIdx.x * 32 + row;
  const float* Qb; const float* Kb; const float* Vb;
  if (dir == 0){ Qb = PL;       Kb = PM;       Vb = PM + 128; }
  else         { Qb = PM + 256; Kb = PL + 128; Vb = PL + 256; }
  const size_t rowb = (size_t)b * L_;
  const float4* qp = (const float4*)(Qb + (rowb + qg)*384 + hh*32);
  float4 q0=qp[0], q1=qp[1], q2=qp[2], q3=qp[3], q4=qp[4], q5=qp[5], q6=qp[6], q7=qp[7];
  float4 o0,o1,o2,o3,o4,o5,o6,o7;
  o0.x=0;o0.y=0;o0.z=0;o0.w=0; o1=o0; o2=o0; o3=o0; o4=o0; o5=o0; o6=o0; o7=o0;
  float m = -1e30f, l = 0.f;
  const float scale = 0.17677669529663687f;  // 1/sqrt(32)
  for (int kk=0;kk<64;kk++){
    const int k = sp*64 + kk;
    const float4* kr = (const float4*)(Kb + (rowb + k)*384 + hh*32);
    float4 kA=kr[0],kB=kr[1],kC=kr[2],kD=kr[3],kE=kr[4],kF=kr[5],kG=kr[6],kH=kr[7];
    float d0=0.f,d1=0.f,d2=0.f,d3=0.f;
    DOT4(q0,kA) DOT4(q1,kB) DOT4(q2,kC) DOT4(q3,kD)
    DOT4(q4,kE) DOT4(q5,kF) DOT4(q6,kG) DOT4(q7,kH)
    float s4 = ((d0+d1)+(d2+d3))*scale;
    if (s4 > m + 8.f){        // defer-max: rare rescale
      float corr = fexpf_(m - s4);
      l *= corr;
      SC4(o0) SC4(o1) SC4(o2) SC4(o3) SC4(o4) SC4(o5) SC4(o6) SC4(o7)
      m = s4;
    }
    float p_ = fexpf_(s4 - m);
    l += p_;
    const float4* vr = (const float4*)(Vb + (rowb + k)*384 + hh*32);
    float4 vA=vr[0],vB=vr[1],vC=vr[2],vD=vr[3],vE=vr[4],vF=vr[5],vG=vr[6],vH=vr[7];
    PV4(o0,vA) PV4(o1,vB) PV4(o2,vC) PV4(o3,vD)
    PV4(o4,vE) PV4(o5,vF) PV4(o6,vG) PV4(o7,vH)
  }
  ST2(0,o0.x,o0.y)  ST2(1,o0.z,o0.w)  ST2(2,o1.x,o1.y)  ST2(3,o1.z,o1.w)
  ST2(4,o2.x,o2.y)  ST2(5,o2.z,o2.w)  ST2(6,o3.x,o3.y)  ST2(7,o3.z,o3.w)
  ST2(8,o4.x,o4.y)  ST2(9,o4.z,o4.w)  ST2(10,o5.x,o5.y) ST2(11,o5.z,o5.w)
  ST2(12,o6.x,o6.y) ST2(13,o6.z,o6.w) ST2(14,o7.x,o7.y) ST2(15,o7.z,o7.w)
  sml[sp][row][0] = m; sml[sp][row][1] = l;
  __syncthreads();
  const int mr = tid >> 4, dp = tid & 15;
  float M = -1e30f;
  #pragma unroll
  for (int s2=0;s2<16;s2++) M = fmaxf(M, sml[s2][mr][0]);
  float Lt = 0.f;
  v2f acc; acc.x=0.f; acc.y=0.f;
  #pragma unroll
  for (int s2=0;s2<16;s2++){
    float w = fexpf_(sml[s2][mr][0] - M);
    Lt = fmaf(sml[s2][mr][1], w, Lt);
    v2f t = po2[s2][mr][dp];
    acc.x = fmaf(t.x, w, acc.x);
    acc.y = fmaf(t.y, w, acc.y);
  }
  float inv = __builtin_amdgcn_rcpf(Lt);
  float* op = AO + (size_t)dir*BL_*128 + (rowb + blockIdx.x*32 + mr)*128 + hh*32;
  v2f outv; outv.x = acc.x*inv; outv.y = acc.y*inv;
  *(v2f*)(op + 2*dp) = outv;
}

// ---------------- residual + LayerNorm ----------------
__global__ __launch_bounds__(64) void ln_kernel(
    const float* __restrict__ HL, const float* __restrict__ T0,
    const float* __restrict__ HM, const float* __restrict__ T1,
    const float* __restrict__ ln_g, const float* __restrict__ ln_b,
    float* __restrict__ HLu, float* __restrict__ HMu)
{
  const int row = blockIdx.x;
  const int which = blockIdx.y;
  const float* X = which ? HM : HL;
  const float* T = which ? T1 : T0;
  const float* g = ln_g + which*128;
  const float* bb = ln_b + which*128;
  float* O = which ? HMu : HLu;
  const int lane = threadIdx.x;
  float v0 = X[(size_t)row*128 + lane]      + T[(size_t)row*128 + lane];
  float v1 = X[(size_t)row*128 + 64 + lane] + T[(size_t)row*128 + 64 + lane];
  float s = v0 + v1, s2 = v0*v0 + v1*v1;
  #pragma unroll
  for (int off=1; off<64; off<<=1){ s += __shfl_xor(s,off); s2 += __shfl_xor(s2,off); }
  float mean = s * (1.f/128.f);
  float var = s2 * (1.f/128.f) - mean*mean;
  float r = rsqrtf(var + 1e-5f);
  O[(size_t)row*128 + lane]      = (v0 - mean)*r*g[lane]      + bb[lane];
  O[(size_t)row*128 + 64 + lane] = (v1 - mean)*r*g[64+lane]   + bb[64+lane];
}

// ---------------- mean pool ----------------
__global__ __launch_bounds__(128) void pool_kernel(
    const float* __restrict__ HMu, const float* __restrict__ HLu,
    float* __restrict__ pooled)
{
  const int whichhalf = blockIdx.x;
  const int b = blockIdx.y;
  const int d = threadIdx.x;
  const float* S = whichhalf ? HLu : HMu;
  float s = 0.f;
  for (int t=0;t<L_;t++) s += S[((size_t)b*L_ + t)*128 + d];
  pooled[b*256 + whichhalf*128 + d] = s * (1.f/1024.f);
}

// ---------------- final MLP ----------------
__global__ __launch_bounds__(128) void fc_kernel(
    const float* __restrict__ pooled,
    const float* __restrict__ fc1_w, const float* __restrict__ fc1_b,
    const float* __restrict__ fc2_w, const float* __restrict__ fc2_b,
    float* __restrict__ out)
{
  const int b = blockIdx.x;
  const int j = threadIdx.x;
  __shared__ float hid[128];
  float acc = fc1_b[j];
  for (int k=0;k<256;k++) acc = fmaf(pooled[b*256 + k], fc1_w[k*128 + j], acc);
  hid[j] = fmaxf(acc, 0.f);
  __syncthreads();
  if (j < NCLS_){
    float a = fc2_b[j];
    for (int k=0;k<128;k++) a = fmaf(hid[k], fc2_w[k*NCLS_ + j], a);
    out[b*NCLS_ + j] = a;
  }
}

extern "C" void kernel_launch(void* const* d_in, const int* in_sizes, int n_in,
                              void* d_out, int out_size, void* d_ws, size_t ws_size,
                              hipStream_t stream)
{
  const float* x            = (const float*)d_in[0];
  const float* mamba_proj_w = (const float*)d_in[1];
  const float* mamba_proj_b = (const float*)d_in[2];
  const float* in_proj_w    = (const float*)d_in[3];
  const float* conv_w       = (const float*)d_in[4];
  const float* conv_b       = (const float*)d_in[5];
  const float* x_proj_w     = (const float*)d_in[6];
  const float* dt_proj_w    = (const float*)d_in[7];
  const float* dt_proj_b    = (const float*)d_in[8];
  const float* A_log        = (const float*)d_in[9];
  const float* Dp           = (const float*)d_in[10];
  const float* out_proj_w   = (const float*)d_in[11];
  const float* lstm_w_ih    = (const float*)d_in[12];
  const float* lstm_w_hh    = (const float*)d_in[13];
  const float* lstm_b       = (const float*)d_in[14];
  const float* ca_w         = (const float*)d_in[15];
  const float* ca_b         = (const float*)d_in[16];
  const float* ln_g         = (const float*)d_in[17];
  const float* ln_b         = (const float*)d_in[18];
  const float* fc1_w        = (const float*)d_in[19];
  const float* fc1_b        = (const float*)d_in[20];
  const float* fc2_w        = (const float*)d_in[21];
  const float* fc2_b        = (const float*)d_in[22];

  float* ws     = (float*)d_ws;
  float* u      = ws + OFF_U;
  float* xc     = ws + OFF_XC;
  float* dbl    = ws + OFF_DBL;
  float* delta  = ws + OFF_DELTA;
  float* yg     = ws + OFF_YG;
  float* xz     = ws + OFF_XZ;
  float* xg     = ws + OFF_XG;
  float* HM     = ws + OFF_HM;
  float* HL     = ws + OFF_HL;
  float* wpk    = ws + OFF_WPK;
  float* wq     = ws + OFF_WQ;
  float* PLb    = ws + OFF_PL;
  float* PMb    = ws + OFF_PM;
  float* AObase = ws + OFF_AO0;
  float* AO0    = ws + OFF_AO0;
  float* AO1    = ws + OFF_AO1;
  float* T0     = ws + OFF_T0;
  float* T1     = ws + OFF_T1;
  float* HLu    = ws + OFF_HLU;
  float* HMu    = ws + OFF_HMU;
  float* pooled = ws + OFF_POOL;

  // ---- phase 0: weight packing ----
  pack_kernel<<<dim3(256),256,0,stream>>>(ca_w, ca_b, lstm_w_ih, lstm_b, lstm_w_hh, wpk, wq);

  // ---- phase 1: projections for both branches ----
  gemm_kernel<<<dim3(2,128),256,0,stream>>>(x, 12, mamba_proj_w, mamba_proj_b, u, BL_, 128, 12, 0);
  gemm128_kernel<<<dim3(4,64),256,0,stream>>>(u, 128, in_proj_w, nullptr, xz, BL_, 512, 128, 0);
  conv_silu_kernel<<<dim3(BL_*DI_/256),256,0,stream>>>(xz, conv_w, conv_b, xc);
  gemm_kernel<<<dim3(1,128),256,0,stream>>>(xc, 256, x_proj_w, nullptr, dbl, BL_, 40, 256, 0);
  gemm128_kernel<<<dim3(2,64),256,0,stream>>>(dbl, 40, dt_proj_w, dt_proj_b, delta, BL_, 256, 8, 1);
  gemm_kernel<<<dim3(8,128),256,0,stream>>>(x, 12, wpk + 99072, wpk + 105216, xg, BL_, 512, 12, 0);

  // ---- phase 2: both recurrences in one launch ----
  scan_lstm_kernel<<<dim3(40),1024,0,stream>>>(delta, dbl, xc, xz, A_log, Dp, yg,
                                               xg, wq, HL);

  // ---- phase 3: cross attention ----
  gemm128_kernel<<<dim3(1,64),256,0,stream>>>(yg, 256, out_proj_w, nullptr, HM, BL_, 128, 256, 0);
  gemm128_kernel<<<dim3(3,64),256,0,stream>>>(HL, 128, wpk,         wpk + 98304, PLb, BL_, 384, 128, 0);
  gemm128_kernel<<<dim3(3,64),256,0,stream>>>(HM, 128, wpk + 49152, wpk + 98688, PMb, BL_, 384, 128, 0);
  attn_kernel<<<dim3(32,32,2),512,0,stream>>>(PLb, PMb, AObase);
  gemm128_kernel<<<dim3(1,64),256,0,stream>>>(AO0, 128, ca_w + 3*16384, ca_b + 384, T0, BL_, 128, 128, 0);
  gemm128_kernel<<<dim3(1,64),256,0,stream>>>(AO1, 128, ca_w + 7*16384, ca_b + 896, T1, BL_, 128, 128, 0);

  // ---- phase 4: LN, pool, MLP ----
  ln_kernel<<<dim3(8192,2),64,0,stream>>>(HL, T0, HM, T1, ln_g, ln_b, HLu, HMu);
  pool_kernel<<<dim3(2,8),128,0,stream>>>(HMu, HLu, pooled);
  fc_kernel<<<dim3(8),128,0,stream>>>(pooled, fc1_w, fc1_b, fc2_w, fc2_b, (float*)d_out);
}